// Round 1
// baseline (154.421 us; speedup 1.0000x reference)
//
#include <hip/hip_runtime.h>
#include <math.h>

// Problem constants
#define BB    4
#define CIN   256
#define HH    64
#define WWID  64
#define COUT  256
#define KKS   3
#define K2    9
#define PADV  1
#define HWSZ  4096
#define GROUPS 32
#define CPG   8
#define EPSV  1e-5f
#define ROWB  4608          // K2*CIN * sizeof(bf16)
#define NKC   36            // K chunks of 64

typedef __attribute__((ext_vector_type(8))) short bf16x8;
typedef __attribute__((ext_vector_type(4))) float f32x4;
typedef __attribute__((ext_vector_type(2))) float f32x2;

#define GLOAD_LDS16(g, l) \
    __builtin_amdgcn_global_load_lds((const __attribute__((address_space(1))) unsigned int*)(g), \
                                     (__attribute__((address_space(3))) unsigned int*)(l), 16, 0, 0)

__device__ __forceinline__ unsigned short f2bf(float f) {
    unsigned u = __float_as_uint(f);
    u = (u + 0x7fffu + ((u >> 16) & 1u)) >> 16;   // RNE
    return (unsigned short)u;
}
// unpack one dword (2 bf16) to a packed float2 for v_pk_fma_f32
__device__ __forceinline__ f32x2 up2(unsigned q) {
    f32x2 v;
    v.x = __uint_as_float(q << 16);
    v.y = __uint_as_float(q & 0xffff0000u);
    return v;
}
// hardware packed f32->2xbf16 (RNE) — T12-verified recipe
__device__ __forceinline__ unsigned cvtpk(f32x2 f) {
    unsigned r;
    asm("v_cvt_pk_bf16_f32 %0, %1, %2" : "=v"(r) : "v"(f.x), "v"(f.y));
    return r;
}

// ---------------------------------------------------------------------------
// k_pre: grid (129, 8, 4).
//  bx<128 : x NCHW -> NHWC bf16 tile transpose
//  bx==128: weight [Cout][Cin][K2] -> bf16 [co][k2][q(64ch)][chunk c^(co&7)]
//           block (128,0,0) zeroes gstat (strided loop covers all 264)
// ---------------------------------------------------------------------------
__global__ __launch_bounds__(256)
void k_pre(const float* __restrict__ x, unsigned short* __restrict__ xh,
           const float* __restrict__ w, unsigned short* __restrict__ wtb,
           float* __restrict__ gstat) {
    int t = threadIdx.x;
    if (blockIdx.x < 128) {
        __shared__ float tile[32][33];
        int hw0 = blockIdx.x * 32;
        int c0  = blockIdx.y * 32;
        int b   = blockIdx.z;
        int tx = t & 31, ty = t >> 5;
        const float* xp = x + (size_t)b * CIN * HWSZ;
        #pragma unroll
        for (int i = 0; i < 4; i++)
            tile[ty + i * 8][tx] = xp[(c0 + ty + i * 8) * HWSZ + hw0 + tx];
        __syncthreads();
        int j = t >> 3, cq = t & 7;
        union { unsigned short s[4]; uint2 d; } pk;
        #pragma unroll
        for (int k = 0; k < 4; k++) pk.s[k] = f2bf(tile[cq * 4 + k][j]);
        *(uint2*)((char*)xh + ((size_t)b * HWSZ * CIN + (size_t)(hw0 + j) * CIN + c0 + cq * 4) * 2) = pk.d;
    } else {
        if (blockIdx.y == 0 && blockIdx.z == 0)
            for (int i = t; i < BB * GROUPS * 2 + 8; i += 256) gstat[i] = 0.f;
        int idx = (blockIdx.y * 4 + blockIdx.z) * 256 + t;   // [0,8192)
        int co = idx >> 5, c8 = idx & 31;
        int cin0 = c8 * 8;
        int q = c8 >> 3, c = c8 & 7;
        int pc = c ^ (co & 7);
        for (int k2 = 0; k2 < K2; k2++) {
            union { unsigned short s[8]; uint4 qq; } pk;
            #pragma unroll
            for (int j = 0; j < 8; j++)
                pk.s[j] = f2bf(w[(co * CIN + cin0 + j) * K2 + k2]);
            int phys = co * ROWB + k2 * 512 + q * 128 + pc * 16;
            *(uint4*)((char*)wtb + phys) = pk.qq;
        }
    }
}

// ---------------------------------------------------------------------------
// k_conv: fused-sampling implicit GEMM, mt-DEDUPED.
// 512 blocks x 256 thr; per block M=256 (ALL couts) x N=32 px strip.
// B tile sampled/packed exactly ONCE per strip (was 2x across m-halves).
// K = 2304 in 36 x BK=64. Per thread: 1 pack item (8ch of one px) using
// v_pk_fma_f32 bilinear combine + v_cvt_pk_bf16_f32 repack.
// 4 waves = 4 m-waves (64 rows each), N=32 shared.
// K-loop: [A-glds(kc) x8 + pack Bs(kc)] barrier
//         [issue gathers(kc+1) (regs)] [MFMA(kc)] barrier.
// XCD k = bid&7 owns 64 contiguous strips -> xh slice ~1.1MB + wtb 1.2MB in L2.
// ---------------------------------------------------------------------------
__global__ __launch_bounds__(256)
void k_conv(const unsigned short* __restrict__ wtb, const unsigned short* __restrict__ xh,
            const float* __restrict__ offset, const float* __restrict__ mask,
            const float* __restrict__ bias, float* __restrict__ out,
            float* __restrict__ gstat) {
    __shared__ __align__(16) unsigned short As[256 * 64];   // 32 KB
    __shared__ __align__(16) unsigned short Bs[32 * 64];    // 4 KB
    __shared__ __align__(16) int   cidx[32 * K2 * 4];       // 4.5 KB (byte offsets, <<9)
    __shared__ __align__(16) float cwgt[32 * K2 * 4];       // 4.5 KB
    __shared__ float gs[32], gss[32];

    // block decode: XCD k = bid&7 owns strips k*64..k*64+63 (contiguous hw)
    int lid = blockIdx.x;
    int strip = (lid & 7) * 64 + (lid >> 3);   // 0..511
    int b = strip >> 7;
    int hwbase = (strip & 127) * 32;

    int t = threadIdx.x, w = t >> 6, l = t & 63;
    int r16 = l & 15, hf = l >> 4;
    int skey = r16 & 7;

    if (t < 32) { gs[t] = 0.f; gss[t] = 0.f; }

    // ---- corner prep: 288 (px,k2) pairs
    for (int i = t; i < 32 * K2; i += 256) {
        int px = i / K2, k2 = i - px * K2;
        int hw = hwbase + px;
        int ho = hw >> 6, wo = hw & 63;
        int ky = k2 / KKS, kx = k2 - ky * KKS;
        float dy = offset[((b * (2 * K2) + k2 * 2 + 0) * HWSZ) + hw];
        float dx = offset[((b * (2 * K2) + k2 * 2 + 1) * HWSZ) + hw];
        float m  = mask[(b * K2 + k2) * HWSZ + hw];
        float y  = (float)(ky + ho - PADV) + dy;
        float xc = (float)(kx + wo - PADV) + dx;
        float y0f = floorf(y), x0f = floorf(xc);
        float fy = y - y0f, fx = xc - x0f;
        int y0 = (int)y0f, x0 = (int)x0f;
        int   yy[2] = { y0, y0 + 1 };
        int   xx[2] = { x0, x0 + 1 };
        float wy[2] = { 1.f - fy, fy };
        float wx[2] = { 1.f - fx, fx };
        #pragma unroll
        for (int ii = 0; ii < 2; ii++)
            #pragma unroll
            for (int jj = 0; jj < 2; jj++) {
                int yi = yy[ii], xi = xx[jj];
                bool valid = (yi >= 0) && (yi < HH) && (xi >= 0) && (xi < WWID);
                int yc  = min(max(yi, 0), HH - 1);
                int xcc = min(max(xi, 0), WWID - 1);
                cidx[i * 4 + ii * 2 + jj] = (yc * WWID + xcc) << 9;   // byte offset (512B/px row)
                cwgt[i * 4 + ii * 2 + jj] = valid ? (wy[ii] * wx[jj] * m) : 0.f;
            }
    }

    // ---- A staging: 2048 x 16B chunks per kc, 8/thread; +128 B per kc
    const char* agb = (const char*)wtb + (size_t)(t >> 3) * ROWB + (t & 7) * 16;
    unsigned short* lA = (unsigned short*)As + t * 8;

    // ---- sampling mapping: 1 item/thread: px = t>>3, sc = t&7
    int sc  = t & 7;
    int px0 = t >> 3;
    const char* xb = (const char*)xh + (size_t)b * HWSZ * CIN * 2 + sc * 16;
    int bofs0 = px0 * 64 + (sc ^ (px0 & 7)) * 8;

    f32x4 acc[4][2];
    #pragma unroll
    for (int mi = 0; mi < 4; mi++)
        #pragma unroll
        for (int ni = 0; ni < 2; ni++) acc[mi][ni] = (f32x4)0.f;

    __syncthreads();   // coef + gs ready

    // prologue gathers for kc=0 (k2=0, q=0)
    uint4 g[4]; float gw[4];
    {
        int cb = (px0 * K2) * 4;
        int4   ci = *(const int4*)&cidx[cb];
        float4 cw = *(const float4*)&cwgt[cb];
        gw[0] = cw.x; gw[1] = cw.y; gw[2] = cw.z; gw[3] = cw.w;
        g[0] = *(const uint4*)(xb + ci.x);
        g[1] = *(const uint4*)(xb + ci.y);
        g[2] = *(const uint4*)(xb + ci.z);
        g[3] = *(const uint4*)(xb + ci.w);
    }

    for (int kc = 0; kc < NKC; kc++) {
        // A: async global->LDS, 8 chunks (rows t>>3 + i*32)
        #pragma unroll
        for (int i = 0; i < 8; i++)
            GLOAD_LDS16(agb + (size_t)i * (32 * (size_t)ROWB), lA + i * 2048);
        agb += 128;

        // pack gathered corners -> Bs (packed f32 math + hw bf16 convert)
        {
            f32x2 f0 = {0.f, 0.f}, f1 = {0.f, 0.f}, f2 = {0.f, 0.f}, f3 = {0.f, 0.f};
            #pragma unroll
            for (int c = 0; c < 4; c++) {
                f32x2 wv = { gw[c], gw[c] };
                f0 = __builtin_elementwise_fma(wv, up2(g[c].x), f0);
                f1 = __builtin_elementwise_fma(wv, up2(g[c].y), f1);
                f2 = __builtin_elementwise_fma(wv, up2(g[c].z), f2);
                f3 = __builtin_elementwise_fma(wv, up2(g[c].w), f3);
            }
            uint4 pk;
            pk.x = cvtpk(f0); pk.y = cvtpk(f1); pk.z = cvtpk(f2); pk.w = cvtpk(f3);
            *(uint4*)&Bs[bofs0] = pk;
        }
        __syncthreads();   // As staged (vmcnt) + Bs written (lgkm)

        // prefetch gathers for kc+1 (register dest — fly during MFMA)
        if (kc < NKC - 1) {
            int kn = kc + 1;
            int k2n = kn >> 2, qn = kn & 3;
            int cb = (px0 * K2 + k2n) * 4;
            int4   ci = *(const int4*)&cidx[cb];
            float4 cw = *(const float4*)&cwgt[cb];
            gw[0] = cw.x; gw[1] = cw.y; gw[2] = cw.z; gw[3] = cw.w;
            const char* xq = xb + qn * 128;
            g[0] = *(const uint4*)(xq + ci.x);
            g[1] = *(const uint4*)(xq + ci.y);
            g[2] = *(const uint4*)(xq + ci.z);
            g[3] = *(const uint4*)(xq + ci.w);
        }

        // MFMA(kc): wave w owns rows w*64..w*64+63, all 32 cols
        #pragma unroll
        for (int ks = 0; ks < 2; ks++) {
            int up = ((ks * 4 + hf) ^ skey) * 8;
            bf16x8 af[4], bv[2];
            #pragma unroll
            for (int mi = 0; mi < 4; mi++)
                af[mi] = *(const bf16x8*)&As[(w * 64 + mi * 16 + r16) * 64 + up];
            #pragma unroll
            for (int ni = 0; ni < 2; ni++)
                bv[ni] = *(const bf16x8*)&Bs[(ni * 16 + r16) * 64 + up];
            #pragma unroll
            for (int mi = 0; mi < 4; mi++)
                #pragma unroll
                for (int ni = 0; ni < 2; ni++)
                    acc[mi][ni] = __builtin_amdgcn_mfma_f32_16x16x32_bf16(
                        af[mi], bv[ni], acc[mi][ni], 0, 0, 0);
        }
        __syncthreads();
    }

    // epilogue: bias + store + GN partials (C/D: col=lane&15 -> n, row=hf*4+reg -> m)
    float s4[4] = {0,0,0,0}, ss4[4] = {0,0,0,0};
    #pragma unroll
    for (int mi = 0; mi < 4; mi++) {
        #pragma unroll
        for (int r = 0; r < 4; r++) {
            int co = w * 64 + mi * 16 + hf * 4 + r;
            float bs = bias[co];
            float* orow = out + ((size_t)(b * COUT + co)) * HWSZ;
            #pragma unroll
            for (int ni = 0; ni < 2; ni++) {
                int n = hwbase + ni * 16 + r16;
                float v = acc[mi][ni][r] + bs;
                orow[n] = v;
                s4[mi] += v; ss4[mi] += v * v;
            }
        }
    }
    int gb = hf >> 1;
    #pragma unroll
    for (int mi = 0; mi < 4; mi++) {
        atomicAdd(&gs [w * 8 + mi * 2 + gb], s4[mi]);
        atomicAdd(&gss[w * 8 + mi * 2 + gb], ss4[mi]);
    }
    __syncthreads();
    if (t < 32) {
        atomicAdd(&gstat[(b * GROUPS + t) * 2 + 0], gs[t]);
        atomicAdd(&gstat[(b * GROUPS + t) * 2 + 1], gss[t]);
    }
}

// ---------------------------------------------------------------------------
// finalize: normalize + affine + ReLU in place (float4)
// ---------------------------------------------------------------------------
__global__ __launch_bounds__(256)
void k_gnfinal(float* __restrict__ out, const float* __restrict__ gstat,
               const float* __restrict__ gamma, const float* __restrict__ beta) {
    int i4 = blockIdx.x * 256 + threadIdx.x;
    int e  = i4 * 4;
    int c  = (e >> 12) & 255;
    int b  = e >> 20;
    int g  = c >> 3;
    float s  = gstat[((b * GROUPS) + g) * 2 + 0];
    float ss = gstat[((b * GROUPS) + g) * 2 + 1];
    const float inv = 1.f / (float)(CPG * HWSZ);
    float mu  = s * inv;
    float var = ss * inv - mu * mu;
    float rstd = rsqrtf(var + EPSV);
    float ga = gamma[c] * rstd;
    float be = beta[c] - mu * ga;
    float4 v = ((float4*)out)[i4];
    v.x = fmaxf(v.x * ga + be, 0.f);
    v.y = fmaxf(v.y * ga + be, 0.f);
    v.z = fmaxf(v.z * ga + be, 0.f);
    v.w = fmaxf(v.w * ga + be, 0.f);
    ((float4*)out)[i4] = v;
}

// ---------------------------------------------------------------------------
extern "C" void kernel_launch(void* const* d_in, const int* in_sizes, int n_in,
                              void* d_out, int out_size, void* d_ws, size_t ws_size,
                              hipStream_t stream) {
    const float* x      = (const float*)d_in[0];
    const float* offset = (const float*)d_in[1];
    const float* mask   = (const float*)d_in[2];
    const float* weight = (const float*)d_in[3];
    const float* bias   = (const float*)d_in[4];
    const float* gamma  = (const float*)d_in[5];
    const float* beta   = (const float*)d_in[6];
    float* out = (float*)d_out;

    // workspace (~10 MB)
    unsigned short* xh    = (unsigned short*)d_ws;              // 4,194,304 us (8.4 MB)
    unsigned short* wtb   = xh + (size_t)4194304;               //   589,824 us (1.2 MB)
    float*          gstat = (float*)(wtb + (size_t)589824);     // 264 f

    k_pre<<<dim3(129, 8, 4), 256, 0, stream>>>(x, xh, weight, wtb, gstat);
    k_conv<<<512, 256, 0, stream>>>(wtb, xh, offset, mask, bias, out, gstat);
    k_gnfinal<<<(size_t)BB * COUT * HWSZ / 1024, 256, 0, stream>>>(out, gstat, gamma, beta);
}

// Round 2
// 152.022 us; speedup vs baseline: 1.0158x; 1.0158x over previous
//
#include <hip/hip_runtime.h>
#include <math.h>

// Problem constants
#define BB    4
#define CIN   256
#define HH    64
#define WWID  64
#define COUT  256
#define KKS   3
#define K2    9
#define PADV  1
#define HWSZ  4096
#define GROUPS 32
#define CPG   8
#define EPSV  1e-5f
#define ROWB  4608          // K2*CIN * sizeof(bf16)
#define NKC   36            // K chunks of 64

typedef __attribute__((ext_vector_type(8))) short bf16x8;
typedef __attribute__((ext_vector_type(4))) float f32x4;
typedef __attribute__((ext_vector_type(2))) float f32x2;

#define GLOAD_LDS16(g, l) \
    __builtin_amdgcn_global_load_lds((const __attribute__((address_space(1))) unsigned int*)(g), \
                                     (__attribute__((address_space(3))) unsigned int*)(l), 16, 0, 0)

__device__ __forceinline__ unsigned short f2bf(float f) {
    unsigned u = __float_as_uint(f);
    u = (u + 0x7fffu + ((u >> 16) & 1u)) >> 16;   // RNE
    return (unsigned short)u;
}
// unpack one dword (2 bf16) to a packed float2 for v_pk_fma_f32
__device__ __forceinline__ f32x2 up2(unsigned q) {
    f32x2 v;
    v.x = __uint_as_float(q << 16);
    v.y = __uint_as_float(q & 0xffff0000u);
    return v;
}
// hardware packed f32->2xbf16 (RNE)
__device__ __forceinline__ unsigned cvtpk(f32x2 f) {
    unsigned r;
    asm("v_cvt_pk_bf16_f32 %0, %1, %2" : "=v"(r) : "v"(f.x), "v"(f.y));
    return r;
}

// ---------------------------------------------------------------------------
// k_pre: grid (129, 8, 4).
//  bx<128 : x NCHW -> NHWC bf16 tile transpose
//  bx==128: weight [Cout][Cin][K2] -> bf16 [co][k2][q(64ch)][chunk c^(co&7)]
//           block (128,0,0) zeroes gstat (strided loop covers all 264)
// ---------------------------------------------------------------------------
__global__ __launch_bounds__(256)
void k_pre(const float* __restrict__ x, unsigned short* __restrict__ xh,
           const float* __restrict__ w, unsigned short* __restrict__ wtb,
           float* __restrict__ gstat) {
    int t = threadIdx.x;
    if (blockIdx.x < 128) {
        __shared__ float tile[32][33];
        int hw0 = blockIdx.x * 32;
        int c0  = blockIdx.y * 32;
        int b   = blockIdx.z;
        int tx = t & 31, ty = t >> 5;
        const float* xp = x + (size_t)b * CIN * HWSZ;
        #pragma unroll
        for (int i = 0; i < 4; i++)
            tile[ty + i * 8][tx] = xp[(c0 + ty + i * 8) * HWSZ + hw0 + tx];
        __syncthreads();
        int j = t >> 3, cq = t & 7;
        union { unsigned short s[4]; uint2 d; } pk;
        #pragma unroll
        for (int k = 0; k < 4; k++) pk.s[k] = f2bf(tile[cq * 4 + k][j]);
        *(uint2*)((char*)xh + ((size_t)b * HWSZ * CIN + (size_t)(hw0 + j) * CIN + c0 + cq * 4) * 2) = pk.d;
    } else {
        if (blockIdx.y == 0 && blockIdx.z == 0)
            for (int i = t; i < BB * GROUPS * 2 + 8; i += 256) gstat[i] = 0.f;
        int idx = (blockIdx.y * 4 + blockIdx.z) * 256 + t;   // [0,8192)
        int co = idx >> 5, c8 = idx & 31;
        int cin0 = c8 * 8;
        int q = c8 >> 3, c = c8 & 7;
        int pc = c ^ (co & 7);
        for (int k2 = 0; k2 < K2; k2++) {
            union { unsigned short s[8]; uint4 qq; } pk;
            #pragma unroll
            for (int j = 0; j < 8; j++)
                pk.s[j] = f2bf(w[(co * CIN + cin0 + j) * K2 + k2]);
            int phys = co * ROWB + k2 * 512 + q * 128 + pc * 16;
            *(uint4*)((char*)wtb + phys) = pk.qq;
        }
    }
}

// ---------------------------------------------------------------------------
// k_conv: fused-sampling implicit GEMM.
// 256 blocks x 512 thr (1 block/CU, 8 waves); per block M=256 x N=64 px.
// K = 2304 in 36 x BK=64. Double-buffered As(2x32KB) + Bs(2x8KB).
// Per K-step: [issue 4 glds(next) + 4 gathers(next)] -> MFMA(cur) ->
//             pack(next) -> ONE __syncthreads. glds/gather latency hides
//             under MFMA+pack; single drain per step (was 2 cold drains).
// Buffers alternate statically (hand-unrolled x2).
// Wave grid 4m x 2n: wave owns M=64 x N=32. XCD k = bid&7 owns 32
// contiguous strips -> xh slice ~1MB + wtb 1.2MB L2-resident.
// ---------------------------------------------------------------------------
#define STAGE(dst) do { \
    _Pragma("unroll") \
    for (int i_ = 0; i_ < 4; i_++) \
        GLOAD_LDS16(agb + (size_t)i_ * (64 * (size_t)ROWB), (dst) + i_ * 4096); \
    agb += 128; \
} while (0)

#define GATHER(kn) do { \
    int k2n_ = (kn) >> 2, qn_ = (kn) & 3; \
    int cb_ = (px0 * K2 + k2n_) * 4; \
    int4   ci_ = *(const int4*)&cidx[cb_]; \
    float4 cw_ = *(const float4*)&cwgt[cb_]; \
    gw[0] = cw_.x; gw[1] = cw_.y; gw[2] = cw_.z; gw[3] = cw_.w; \
    const char* xq_ = xb + qn_ * 128; \
    g[0] = *(const uint4*)(xq_ + ci_.x); \
    g[1] = *(const uint4*)(xq_ + ci_.y); \
    g[2] = *(const uint4*)(xq_ + ci_.z); \
    g[3] = *(const uint4*)(xq_ + ci_.w); \
} while (0)

#define PACK(Bdst) do { \
    f32x2 f0 = {0.f, 0.f}, f1 = {0.f, 0.f}, f2 = {0.f, 0.f}, f3 = {0.f, 0.f}; \
    _Pragma("unroll") \
    for (int c_ = 0; c_ < 4; c_++) { \
        f32x2 wv_ = { gw[c_], gw[c_] }; \
        f0 = __builtin_elementwise_fma(wv_, up2(g[c_].x), f0); \
        f1 = __builtin_elementwise_fma(wv_, up2(g[c_].y), f1); \
        f2 = __builtin_elementwise_fma(wv_, up2(g[c_].z), f2); \
        f3 = __builtin_elementwise_fma(wv_, up2(g[c_].w), f3); \
    } \
    uint4 pk_; \
    pk_.x = cvtpk(f0); pk_.y = cvtpk(f1); pk_.z = cvtpk(f2); pk_.w = cvtpk(f3); \
    *(uint4*)&(Bdst)[bofs0] = pk_; \
} while (0)

#define MFMA_STEP(Ac, Bc) do { \
    __builtin_amdgcn_s_setprio(1); \
    _Pragma("unroll") \
    for (int ks_ = 0; ks_ < 2; ks_++) { \
        int up_ = ((ks_ * 4 + hf) ^ skey) * 8; \
        bf16x8 af_[4], bv_[2]; \
        _Pragma("unroll") \
        for (int mi_ = 0; mi_ < 4; mi_++) \
            af_[mi_] = *(const bf16x8*)&(Ac)[(wm * 64 + mi_ * 16 + r16) * 64 + up_]; \
        _Pragma("unroll") \
        for (int ni_ = 0; ni_ < 2; ni_++) \
            bv_[ni_] = *(const bf16x8*)&(Bc)[(wn * 32 + ni_ * 16 + r16) * 64 + up_]; \
        _Pragma("unroll") \
        for (int mi_ = 0; mi_ < 4; mi_++) \
            _Pragma("unroll") \
            for (int ni_ = 0; ni_ < 2; ni_++) \
                acc[mi_][ni_] = __builtin_amdgcn_mfma_f32_16x16x32_bf16( \
                    af_[mi_], bv_[ni_], acc[mi_][ni_], 0, 0, 0); \
    } \
    __builtin_amdgcn_s_setprio(0); \
} while (0)

#define BODY(kc, Ac, An, Bc, Bn, lAn) do { \
    if ((kc) + 1 < NKC) { \
        STAGE(lAn); \
        GATHER((kc) + 1); \
        __builtin_amdgcn_sched_barrier(0); \
    } \
    MFMA_STEP(Ac, Bc); \
    if ((kc) + 1 < NKC) { \
        PACK(Bn); \
        __syncthreads(); \
    } \
} while (0)

__global__ __launch_bounds__(512, 2)
void k_conv(const unsigned short* __restrict__ wtb, const unsigned short* __restrict__ xh,
            const float* __restrict__ offset, const float* __restrict__ mask,
            const float* __restrict__ bias, float* __restrict__ out,
            float* __restrict__ gstat) {
    __shared__ __align__(16) unsigned short As[2][256 * 64];   // 64 KB
    __shared__ __align__(16) unsigned short Bs[2][64 * 64];    // 16 KB
    __shared__ __align__(16) int   cidx[64 * K2 * 4];          // 9 KB (byte offsets)
    __shared__ __align__(16) float cwgt[64 * K2 * 4];          // 9 KB
    __shared__ float gs[32], gss[32];

    // block decode: XCD k = bid&7 owns strips k*32..k*32+31 (contiguous hw)
    int lid = blockIdx.x;
    int strip = (lid & 7) * 32 + (lid >> 3);   // 0..255
    int b = strip >> 6;
    int hwbase = (strip & 63) * 64;

    int t = threadIdx.x, w = t >> 6, l = t & 63;
    int r16 = l & 15, hf = l >> 4;
    int skey = r16 & 7;
    int wm = w & 3, wn = w >> 2;

    if (t < 32) { gs[t] = 0.f; gss[t] = 0.f; }

    // ---- corner prep: 576 (px,k2) pairs
    for (int i = t; i < 64 * K2; i += 512) {
        int px = i / K2, k2 = i - px * K2;
        int hw = hwbase + px;
        int ho = hw >> 6, wo = hw & 63;
        int ky = k2 / KKS, kx = k2 - ky * KKS;
        float dy = offset[((b * (2 * K2) + k2 * 2 + 0) * HWSZ) + hw];
        float dx = offset[((b * (2 * K2) + k2 * 2 + 1) * HWSZ) + hw];
        float m  = mask[(b * K2 + k2) * HWSZ + hw];
        float y  = (float)(ky + ho - PADV) + dy;
        float xc = (float)(kx + wo - PADV) + dx;
        float y0f = floorf(y), x0f = floorf(xc);
        float fy = y - y0f, fx = xc - x0f;
        int y0 = (int)y0f, x0 = (int)x0f;
        int   yy[2] = { y0, y0 + 1 };
        int   xx[2] = { x0, x0 + 1 };
        float wy[2] = { 1.f - fy, fy };
        float wx[2] = { 1.f - fx, fx };
        #pragma unroll
        for (int ii = 0; ii < 2; ii++)
            #pragma unroll
            for (int jj = 0; jj < 2; jj++) {
                int yi = yy[ii], xi = xx[jj];
                bool valid = (yi >= 0) && (yi < HH) && (xi >= 0) && (xi < WWID);
                int yc  = min(max(yi, 0), HH - 1);
                int xcc = min(max(xi, 0), WWID - 1);
                cidx[i * 4 + ii * 2 + jj] = (yc * WWID + xcc) << 9;   // byte offset (512B/px row)
                cwgt[i * 4 + ii * 2 + jj] = valid ? (wy[ii] * wx[jj] * m) : 0.f;
            }
    }

    // ---- A staging: 2048 x 16B chunks per kc, 4/thread; +128 B per kc
    const char* agb = (const char*)wtb + (size_t)(t >> 3) * ROWB + (t & 7) * 16;
    unsigned short* lA0 = &As[0][t * 8];
    unsigned short* lA1 = &As[1][t * 8];

    // ---- sampling mapping: 1 item/thread: px = t>>3 (0..63), sc = t&7
    int sc  = t & 7;
    int px0 = t >> 3;
    const char* xb = (const char*)xh + (size_t)b * HWSZ * CIN * 2 + sc * 16;
    int bofs0 = px0 * 64 + (sc ^ (px0 & 7)) * 8;

    f32x4 acc[4][2];
    #pragma unroll
    for (int mi = 0; mi < 4; mi++)
        #pragma unroll
        for (int ni = 0; ni < 2; ni++) acc[mi][ni] = (f32x4)0.f;

    __syncthreads();   // coef + gs ready

    // ---- prologue: prepare As[0], Bs[0] for kc=0
    uint4 g[4]; float gw[4];
    GATHER(0);
    STAGE(lA0);
    PACK(Bs[0]);
    __syncthreads();

    // ---- main loop: NKC=36 steps, statically alternating buffers
    for (int kc2 = 0; kc2 < NKC; kc2 += 2) {
        BODY(kc2,     As[0], As[1], Bs[0], Bs[1], lA1);
        BODY(kc2 + 1, As[1], As[0], Bs[1], Bs[0], lA0);
    }

    // epilogue: bias + store + GN partials (C/D: col=lane&15 -> n, row=hf*4+reg -> m)
    float s4[4] = {0,0,0,0}, ss4[4] = {0,0,0,0};
    #pragma unroll
    for (int mi = 0; mi < 4; mi++) {
        #pragma unroll
        for (int r = 0; r < 4; r++) {
            int co = wm * 64 + mi * 16 + hf * 4 + r;
            float bs = bias[co];
            float* orow = out + ((size_t)(b * COUT + co)) * HWSZ;
            #pragma unroll
            for (int ni = 0; ni < 2; ni++) {
                int n = hwbase + wn * 32 + ni * 16 + r16;
                float v = acc[mi][ni][r] + bs;
                orow[n] = v;
                s4[mi] += v; ss4[mi] += v * v;
            }
        }
    }
    int gb = hf >> 1;
    #pragma unroll
    for (int mi = 0; mi < 4; mi++) {
        atomicAdd(&gs [wm * 8 + mi * 2 + gb], s4[mi]);
        atomicAdd(&gss[wm * 8 + mi * 2 + gb], ss4[mi]);
    }
    __syncthreads();
    if (t < 32) {
        atomicAdd(&gstat[(b * GROUPS + t) * 2 + 0], gs[t]);
        atomicAdd(&gstat[(b * GROUPS + t) * 2 + 1], gss[t]);
    }
}

// ---------------------------------------------------------------------------
// finalize: normalize + affine + ReLU in place (float4)
// ---------------------------------------------------------------------------
__global__ __launch_bounds__(256)
void k_gnfinal(float* __restrict__ out, const float* __restrict__ gstat,
               const float* __restrict__ gamma, const float* __restrict__ beta) {
    int i4 = blockIdx.x * 256 + threadIdx.x;
    int e  = i4 * 4;
    int c  = (e >> 12) & 255;
    int b  = e >> 20;
    int g  = c >> 3;
    float s  = gstat[((b * GROUPS) + g) * 2 + 0];
    float ss = gstat[((b * GROUPS) + g) * 2 + 1];
    const float inv = 1.f / (float)(CPG * HWSZ);
    float mu  = s * inv;
    float var = ss * inv - mu * mu;
    float rstd = rsqrtf(var + EPSV);
    float ga = gamma[c] * rstd;
    float be = beta[c] - mu * ga;
    float4 v = ((float4*)out)[i4];
    v.x = fmaxf(v.x * ga + be, 0.f);
    v.y = fmaxf(v.y * ga + be, 0.f);
    v.z = fmaxf(v.z * ga + be, 0.f);
    v.w = fmaxf(v.w * ga + be, 0.f);
    ((float4*)out)[i4] = v;
}

// ---------------------------------------------------------------------------
extern "C" void kernel_launch(void* const* d_in, const int* in_sizes, int n_in,
                              void* d_out, int out_size, void* d_ws, size_t ws_size,
                              hipStream_t stream) {
    const float* x      = (const float*)d_in[0];
    const float* offset = (const float*)d_in[1];
    const float* mask   = (const float*)d_in[2];
    const float* weight = (const float*)d_in[3];
    const float* bias   = (const float*)d_in[4];
    const float* gamma  = (const float*)d_in[5];
    const float* beta   = (const float*)d_in[6];
    float* out = (float*)d_out;

    // workspace (~10 MB)
    unsigned short* xh    = (unsigned short*)d_ws;              // 4,194,304 us (8.4 MB)
    unsigned short* wtb   = xh + (size_t)4194304;               //   589,824 us (1.2 MB)
    float*          gstat = (float*)(wtb + (size_t)589824);     // 264 f

    k_pre<<<dim3(129, 8, 4), 256, 0, stream>>>(x, xh, weight, wtb, gstat);
    k_conv<<<256, 512, 0, stream>>>(wtb, xh, offset, mask, bias, out, gstat);
    k_gnfinal<<<(size_t)BB * COUT * HWSZ / 1024, 256, 0, stream>>>(out, gstat, gamma, beta);
}

// Round 4
// 146.237 us; speedup vs baseline: 1.0560x; 1.0396x over previous
//
#include <hip/hip_runtime.h>
#include <math.h>

// Problem constants
#define BB    4
#define CIN   256
#define HH    64
#define WWID  64
#define COUT  256
#define KKS   3
#define K2    9
#define PADV  1
#define HWSZ  4096
#define GROUPS 32
#define CPG   8
#define EPSV  1e-5f
#define NKC   36            // K chunks of 64

typedef __attribute__((ext_vector_type(8))) short bf16x8;
typedef __attribute__((ext_vector_type(4))) float f32x4;
typedef __attribute__((ext_vector_type(2))) float f32x2;

__device__ __forceinline__ unsigned short f2bf(float f) {
    unsigned u = __float_as_uint(f);
    u = (u + 0x7fffu + ((u >> 16) & 1u)) >> 16;   // RNE
    return (unsigned short)u;
}
__device__ __forceinline__ f32x2 up2(unsigned q) {
    f32x2 v;
    v.x = __uint_as_float(q << 16);
    v.y = __uint_as_float(q & 0xffff0000u);
    return v;
}
__device__ __forceinline__ unsigned cvtpk(f32x2 f) {
    unsigned r;
    asm("v_cvt_pk_bf16_f32 %0, %1, %2" : "=v"(r) : "v"(f.x), "v"(f.y));
    return r;
}

// ---------------------------------------------------------------------------
// k_pre: grid (65, 8, 4).
//  bx<64 : x NCHW -> NHWC bf16 transpose, 32c x 64hw tiles
//  bx==64: weight [Cout][Cin][K2] -> FRAGMENT-major wtb:
//          byte addr = ((co>>4)*36 + kc)*2048 + ks*1024 + (hf*16 + (co&15))*16
//          so one MFMA A-fragment (lane l reads bytes l*16..l*16+15) is a
//          single 1KB contiguous, fully-coalesced global_load_dwordx4.
//          block (64,0,0) zeroes gstat.
// ---------------------------------------------------------------------------
__global__ __launch_bounds__(256)
void k_pre(const float* __restrict__ x, unsigned short* __restrict__ xh,
           const float* __restrict__ w, unsigned short* __restrict__ wtb,
           float* __restrict__ gstat) {
    int t = threadIdx.x;
    if (blockIdx.x < 64) {
        __shared__ float tile[32][65];
        int hw0 = blockIdx.x * 64;
        int c0  = blockIdx.y * 32;
        int b   = blockIdx.z;
        const float* xp = x + (size_t)b * CIN * HWSZ;
        int col = t & 63, r0 = t >> 6;
        #pragma unroll
        for (int i = 0; i < 8; i++)
            tile[i * 4 + r0][col] = xp[(c0 + i * 4 + r0) * HWSZ + hw0 + col];
        __syncthreads();
        int hw = t >> 2, cq = t & 3;
        union { unsigned short s[8]; uint4 qq; } pk;
        #pragma unroll
        for (int k = 0; k < 8; k++) pk.s[k] = f2bf(tile[cq * 8 + k][hw]);
        *(uint4*)((char*)xh + (((size_t)b * HWSZ + hw0 + hw) * CIN + c0 + cq * 8) * 2) = pk.qq;
    } else {
        if (blockIdx.y == 0 && blockIdx.z == 0)
            for (int i = t; i < BB * GROUPS * 2 + 8; i += 256) gstat[i] = 0.f;
        int idx = (blockIdx.y * 4 + blockIdx.z) * 256 + t;   // [0,8192)
        int co = idx >> 5, c8 = idx & 31;
        int q  = c8 >> 3;                // 64-ch chunk within 256
        int ks = (c8 & 7) >> 2;          // K-half within 64-chunk
        int hf = c8 & 3;                 // 8-ch slice within 32
        int lane16 = hf * 16 + (co & 15);
        for (int k2 = 0; k2 < K2; k2++) {
            int kc = k2 * 4 + q;
            union { unsigned short s[8]; uint4 qq; } pk;
            #pragma unroll
            for (int j = 0; j < 8; j++)
                pk.s[j] = f2bf(w[(co * CIN + c8 * 8 + j) * K2 + k2]);
            size_t phys = (size_t)(((co >> 4) * 36 + kc)) * 2048 + ks * 1024 + lane16 * 16;
            *(uint4*)((char*)wtb + phys) = pk.qq;
        }
    }
}

// ---------------------------------------------------------------------------
// k_conv: fused-sampling implicit GEMM.
// 256 blocks x 512 thr (8 waves: 4m x 2n). M=256 x N=64, K=2304 in 36x64.
// A: NO LDS — fragment-major wtb read straight to regs (8 x 1KB coalesced
//    loads/wave/step), register double-buffered one step ahead.
// B: gathers 2-deep prefetched into regs, pack v_pk_fma + cvt_pk_bf16,
//    Bs LDS double-buffered.
// ALL VMEM register-destined -> compiler emits counted vmcnt; the per-step
// barrier is lgkmcnt-only (Bs handoff) — vmcnt is NEVER drained in-loop.
// ---------------------------------------------------------------------------
#define GATHER2(garr, gwarr, kn) do { \
    int k2n_ = (kn) >> 2, qn_ = (kn) & 3; \
    int cb_ = (px0 * K2 + k2n_) * 4; \
    int4   ci_ = *(const int4*)&cidx[cb_]; \
    float4 cw_ = *(const float4*)&cwgt[cb_]; \
    gwarr[0] = cw_.x; gwarr[1] = cw_.y; gwarr[2] = cw_.z; gwarr[3] = cw_.w; \
    const char* xq_ = xb + qn_ * 128; \
    garr[0] = *(const uint4*)(xq_ + ci_.x); \
    garr[1] = *(const uint4*)(xq_ + ci_.y); \
    garr[2] = *(const uint4*)(xq_ + ci_.z); \
    garr[3] = *(const uint4*)(xq_ + ci_.w); \
} while (0)

#define ISSUE_A(Ar) do { \
    Ar[0] = *(const bf16x8*)(ap0);        Ar[1] = *(const bf16x8*)(ap0 + 1024); \
    Ar[2] = *(const bf16x8*)(ap1);        Ar[3] = *(const bf16x8*)(ap1 + 1024); \
    Ar[4] = *(const bf16x8*)(ap2);        Ar[5] = *(const bf16x8*)(ap2 + 1024); \
    Ar[6] = *(const bf16x8*)(ap3);        Ar[7] = *(const bf16x8*)(ap3 + 1024); \
    ap0 += 2048; ap1 += 2048; ap2 += 2048; ap3 += 2048; \
} while (0)

#define PACK(garr, gwarr, Bdst) do { \
    f32x2 f0 = {0.f, 0.f}, f1 = {0.f, 0.f}, f2 = {0.f, 0.f}, f3 = {0.f, 0.f}; \
    _Pragma("unroll") \
    for (int c_ = 0; c_ < 4; c_++) { \
        f32x2 wv_ = { gwarr[c_], gwarr[c_] }; \
        f0 = __builtin_elementwise_fma(wv_, up2(garr[c_].x), f0); \
        f1 = __builtin_elementwise_fma(wv_, up2(garr[c_].y), f1); \
        f2 = __builtin_elementwise_fma(wv_, up2(garr[c_].z), f2); \
        f3 = __builtin_elementwise_fma(wv_, up2(garr[c_].w), f3); \
    } \
    uint4 pk_; \
    pk_.x = cvtpk(f0); pk_.y = cvtpk(f1); pk_.z = cvtpk(f2); pk_.w = cvtpk(f3); \
    *(uint4*)&(Bdst)[bofs0] = pk_; \
} while (0)

#define MFMA_STEP(Ar, Bc) do { \
    __builtin_amdgcn_s_setprio(1); \
    _Pragma("unroll") \
    for (int ks_ = 0; ks_ < 2; ks_++) { \
        int up_ = ((ks_ * 4 + hf) ^ skey) * 8; \
        bf16x8 bv_[2]; \
        _Pragma("unroll") \
        for (int ni_ = 0; ni_ < 2; ni_++) \
            bv_[ni_] = *(const bf16x8*)&(Bc)[(wn * 32 + ni_ * 16 + r16) * 64 + up_]; \
        _Pragma("unroll") \
        for (int mi_ = 0; mi_ < 4; mi_++) \
            _Pragma("unroll") \
            for (int ni_ = 0; ni_ < 2; ni_++) \
                acc[mi_][ni_] = __builtin_amdgcn_mfma_f32_16x16x32_bf16( \
                    Ar[mi_ * 2 + ks_], bv_[ni_], acc[mi_][ni_], 0, 0, 0); \
    } \
    __builtin_amdgcn_s_setprio(0); \
} while (0)

// lgkm-only barrier: Bs ds_writes drained; in-flight VMEM (A regs, gathers)
// keeps flying across it. sched_barrier pins placement (rule #18).
#define LGKM_BAR() do { \
    asm volatile("s_waitcnt lgkmcnt(0)\n\ts_barrier" ::: "memory"); \
    __builtin_amdgcn_sched_barrier(0); \
} while (0)

#define BODY(kc, Acur, Anxt, Bcur, Bnxt, gU, gwU, gF, gwF) do { \
    ISSUE_A(Anxt); \
    GATHER2(gF, gwF, (kc) + 2); \
    __builtin_amdgcn_sched_barrier(0); \
    MFMA_STEP(Acur, Bcur); \
    __builtin_amdgcn_sched_barrier(0); \
    PACK(gU, gwU, Bnxt); \
    LGKM_BAR(); \
} while (0)

__global__ __launch_bounds__(512, 2)
void k_conv(const unsigned short* __restrict__ wtb, const unsigned short* __restrict__ xh,
            const float* __restrict__ offset, const float* __restrict__ mask,
            const float* __restrict__ bias, float* __restrict__ out,
            float* __restrict__ gstat) {
    __shared__ __align__(16) unsigned short Bs[2][64 * 64];    // 16 KB
    __shared__ __align__(16) int   cidx[64 * K2 * 4];          // 9 KB (byte offsets)
    __shared__ __align__(16) float cwgt[64 * K2 * 4];          // 9 KB
    __shared__ float gs[32], gss[32];

    // block decode: XCD k = bid&7 owns strips k*32..k*32+31 (contiguous hw)
    int lid = blockIdx.x;
    int strip = (lid & 7) * 32 + (lid >> 3);   // 0..255
    int b = strip >> 6;
    int hwbase = (strip & 63) * 64;

    int t = threadIdx.x, w = t >> 6, l = t & 63;
    int r16 = l & 15, hf = l >> 4;
    int skey = r16 & 7;
    int wm = w & 3, wn = w >> 2;

    if (t < 32) { gs[t] = 0.f; gss[t] = 0.f; }

    // ---- corner prep: 576 (px,k2) pairs
    for (int i = t; i < 64 * K2; i += 512) {
        int px = i / K2, k2 = i - px * K2;
        int hw = hwbase + px;
        int ho = hw >> 6, wo = hw & 63;
        int ky = k2 / KKS, kx = k2 - ky * KKS;
        float dy = offset[((b * (2 * K2) + k2 * 2 + 0) * HWSZ) + hw];
        float dx = offset[((b * (2 * K2) + k2 * 2 + 1) * HWSZ) + hw];
        float m  = mask[(b * K2 + k2) * HWSZ + hw];
        float y  = (float)(ky + ho - PADV) + dy;
        float xc = (float)(kx + wo - PADV) + dx;
        float y0f = floorf(y), x0f = floorf(xc);
        float fy = y - y0f, fx = xc - x0f;
        int y0 = (int)y0f, x0 = (int)x0f;
        int   yy[2] = { y0, y0 + 1 };
        int   xx[2] = { x0, x0 + 1 };
        float wy[2] = { 1.f - fy, fy };
        float wx[2] = { 1.f - fx, fx };
        #pragma unroll
        for (int ii = 0; ii < 2; ii++)
            #pragma unroll
            for (int jj = 0; jj < 2; jj++) {
                int yi = yy[ii], xi = xx[jj];
                bool valid = (yi >= 0) && (yi < HH) && (xi >= 0) && (xi < WWID);
                int yc  = min(max(yi, 0), HH - 1);
                int xcc = min(max(xi, 0), WWID - 1);
                cidx[i * 4 + ii * 2 + jj] = (yc * WWID + xcc) << 9;   // byte offset
                cwgt[i * 4 + ii * 2 + jj] = valid ? (wy[ii] * wx[jj] * m) : 0.f;
            }
    }

    // ---- A fragment pointers: wave wm owns co-tiles wm*4+0..3; +2KB per kc
    const char* wb = (const char*)wtb + (size_t)l * 16;
    const char* ap0 = wb + (size_t)((wm * 4 + 0) * 36) * 2048;
    const char* ap1 = wb + (size_t)((wm * 4 + 1) * 36) * 2048;
    const char* ap2 = wb + (size_t)((wm * 4 + 2) * 36) * 2048;
    const char* ap3 = wb + (size_t)((wm * 4 + 3) * 36) * 2048;

    // ---- sampling mapping: 1 item/thread: px = t>>3 (0..63), sc = t&7
    int sc  = t & 7;
    int px0 = t >> 3;
    const char* xb = (const char*)xh + (size_t)b * HWSZ * CIN * 2 + sc * 16;
    int bofs0 = px0 * 64 + (sc ^ (px0 & 7)) * 8;

    f32x4 acc[4][2];
    #pragma unroll
    for (int mi = 0; mi < 4; mi++)
        #pragma unroll
        for (int ni = 0; ni < 2; ni++) acc[mi][ni] = (f32x4)0.f;

    __syncthreads();   // coef + gs ready

    // ---- prologue
    uint4 gA[4], gB[4]; float gwA[4], gwB[4];
    bf16x8 Aa[8], Ab[8];
    GATHER2(gA, gwA, 0);
    ISSUE_A(Aa);              // A(0)
    GATHER2(gB, gwB, 1);
    PACK(gA, gwA, Bs[0]);     // B(0); waits its gathers (counted), A stays in flight
    LGKM_BAR();

    unsigned short* Bs0 = &Bs[0][0];
    unsigned short* Bs1 = &Bs[1][0];

    // ---- main loop: bodies 0..33 (2-unrolled), then body 34, tail 35
    for (int kc2 = 0; kc2 < 34; kc2 += 2) {
        BODY(kc2,     Aa, Ab, Bs0, Bs1, gB, gwB, gA, gwA);
        BODY(kc2 + 1, Ab, Aa, Bs1, Bs0, gA, gwA, gB, gwB);
    }
    // body 34: issue A(35), MFMA(34), pack B(35) from gB; no gather fill
    ISSUE_A(Ab);
    __builtin_amdgcn_sched_barrier(0);
    MFMA_STEP(Aa, Bs0);
    __builtin_amdgcn_sched_barrier(0);
    PACK(gB, gwB, Bs1);
    LGKM_BAR();
    // tail: kc=35
    MFMA_STEP(Ab, Bs1);

    // ---- epilogue: bias + store + GN partials (C/D: col=lane&15, row=hf*4+r)
    float s4[4] = {0,0,0,0}, ss4[4] = {0,0,0,0};
    #pragma unroll
    for (int mi = 0; mi < 4; mi++) {
        #pragma unroll
        for (int r = 0; r < 4; r++) {
            int co = wm * 64 + mi * 16 + hf * 4 + r;
            float bs = bias[co];
            float* orow = out + ((size_t)(b * COUT + co)) * HWSZ;
            #pragma unroll
            for (int ni = 0; ni < 2; ni++) {
                int n = hwbase + wn * 32 + ni * 16 + r16;
                float v = acc[mi][ni][r] + bs;
                orow[n] = v;
                s4[mi] += v; ss4[mi] += v * v;
            }
        }
    }
    int gb = hf >> 1;
    #pragma unroll
    for (int mi = 0; mi < 4; mi++) {
        atomicAdd(&gs [wm * 8 + mi * 2 + gb], s4[mi]);
        atomicAdd(&gss[wm * 8 + mi * 2 + gb], ss4[mi]);
    }
    __syncthreads();
    if (t < 32) {
        atomicAdd(&gstat[(b * GROUPS + t) * 2 + 0], gs[t]);
        atomicAdd(&gstat[(b * GROUPS + t) * 2 + 1], gss[t]);
    }
}

// ---------------------------------------------------------------------------
// finalize: normalize + affine + ReLU in place (float4)
// ---------------------------------------------------------------------------
__global__ __launch_bounds__(256)
void k_gnfinal(float* __restrict__ out, const float* __restrict__ gstat,
               const float* __restrict__ gamma, const float* __restrict__ beta) {
    int i4 = blockIdx.x * 256 + threadIdx.x;
    int e  = i4 * 4;
    int c  = (e >> 12) & 255;
    int b  = e >> 20;
    int g  = c >> 3;
    float s  = gstat[((b * GROUPS) + g) * 2 + 0];
    float ss = gstat[((b * GROUPS) + g) * 2 + 1];
    const float inv = 1.f / (float)(CPG * HWSZ);
    float mu  = s * inv;
    float var = ss * inv - mu * mu;
    float rstd = rsqrtf(var + EPSV);
    float ga = gamma[c] * rstd;
    float be = beta[c] - mu * ga;
    float4 v = ((float4*)out)[i4];
    v.x = fmaxf(v.x * ga + be, 0.f);
    v.y = fmaxf(v.y * ga + be, 0.f);
    v.z = fmaxf(v.z * ga + be, 0.f);
    v.w = fmaxf(v.w * ga + be, 0.f);
    ((float4*)out)[i4] = v;
}

// ---------------------------------------------------------------------------
extern "C" void kernel_launch(void* const* d_in, const int* in_sizes, int n_in,
                              void* d_out, int out_size, void* d_ws, size_t ws_size,
                              hipStream_t stream) {
    const float* x      = (const float*)d_in[0];
    const float* offset = (const float*)d_in[1];
    const float* mask   = (const float*)d_in[2];
    const float* weight = (const float*)d_in[3];
    const float* bias   = (const float*)d_in[4];
    const float* gamma  = (const float*)d_in[5];
    const float* beta   = (const float*)d_in[6];
    float* out = (float*)d_out;

    // workspace (~10 MB)
    unsigned short* xh    = (unsigned short*)d_ws;              // 4,194,304 us (8.4 MB)
    unsigned short* wtb   = xh + (size_t)4194304;               //   589,824 us (1.2 MB)
    float*          gstat = (float*)(wtb + (size_t)589824);     // 264 f

    k_pre<<<dim3(65, 8, 4), 256, 0, stream>>>(x, xh, weight, wtb, gstat);
    k_conv<<<256, 512, 0, stream>>>(wtb, xh, offset, mask, bias, out, gstat);
    k_gnfinal<<<(size_t)BB * COUT * HWSZ / 1024, 256, 0, stream>>>(out, gstat, gamma, beta);
}

// Round 5
// 144.393 us; speedup vs baseline: 1.0695x; 1.0128x over previous
//
#include <hip/hip_runtime.h>
#include <math.h>

// Problem constants
#define BB    4
#define CIN   256
#define HH    64
#define WWID  64
#define COUT  256
#define KKS   3
#define K2    9
#define PADV  1
#define HWSZ  4096
#define GROUPS 32
#define CPG   8
#define EPSV  1e-5f
#define NKC   36            // K chunks of 64

typedef __attribute__((ext_vector_type(8))) short bf16x8;
typedef __attribute__((ext_vector_type(4))) float f32x4;
typedef __attribute__((ext_vector_type(2))) float f32x2;

__device__ __forceinline__ unsigned short f2bf(float f) {
    unsigned u = __float_as_uint(f);
    u = (u + 0x7fffu + ((u >> 16) & 1u)) >> 16;   // RNE
    return (unsigned short)u;
}
__device__ __forceinline__ f32x2 up2(unsigned q) {
    f32x2 v;
    v.x = __uint_as_float(q << 16);
    v.y = __uint_as_float(q & 0xffff0000u);
    return v;
}
__device__ __forceinline__ unsigned cvtpk(f32x2 f) {
    unsigned r;
    asm("v_cvt_pk_bf16_f32 %0, %1, %2" : "=v"(r) : "v"(f.x), "v"(f.y));
    return r;
}

// ---------------------------------------------------------------------------
// k_pre: grid (65, 8, 4).
//  bx<64 : x NCHW -> NHWC bf16 transpose, 32c x 64hw tiles
//  bx==64: weight [Cout][Cin][K2] -> FRAGMENT-major wtb:
//          byte addr = ((co>>4)*36 + kc)*2048 + ks*1024 + (hf*16 + (co&15))*16
//          so one MFMA A-fragment (lane l reads bytes l*16..l*16+15) is a
//          single 1KB contiguous, fully-coalesced global_load_dwordx4.
//          block (64,0,0) zeroes gstat.
// ---------------------------------------------------------------------------
__global__ __launch_bounds__(256)
void k_pre(const float* __restrict__ x, unsigned short* __restrict__ xh,
           const float* __restrict__ w, unsigned short* __restrict__ wtb,
           float* __restrict__ gstat) {
    int t = threadIdx.x;
    if (blockIdx.x < 64) {
        __shared__ float tile[32][65];
        int hw0 = blockIdx.x * 64;
        int c0  = blockIdx.y * 32;
        int b   = blockIdx.z;
        const float* xp = x + (size_t)b * CIN * HWSZ;
        int col = t & 63, r0 = t >> 6;
        #pragma unroll
        for (int i = 0; i < 8; i++)
            tile[i * 4 + r0][col] = xp[(c0 + i * 4 + r0) * HWSZ + hw0 + col];
        __syncthreads();
        int hw = t >> 2, cq = t & 3;
        union { unsigned short s[8]; uint4 qq; } pk;
        #pragma unroll
        for (int k = 0; k < 8; k++) pk.s[k] = f2bf(tile[cq * 8 + k][hw]);
        *(uint4*)((char*)xh + (((size_t)b * HWSZ + hw0 + hw) * CIN + c0 + cq * 8) * 2) = pk.qq;
    } else {
        if (blockIdx.y == 0 && blockIdx.z == 0)
            for (int i = t; i < BB * GROUPS * 2 + 8; i += 256) gstat[i] = 0.f;
        int idx = (blockIdx.y * 4 + blockIdx.z) * 256 + t;   // [0,8192)
        int co = idx >> 5, c8 = idx & 31;
        int q  = c8 >> 3;                // 64-ch chunk within 256
        int ks = (c8 & 7) >> 2;          // K-half within 64-chunk
        int hf = c8 & 3;                 // 8-ch slice within 32
        int lane16 = hf * 16 + (co & 15);
        for (int k2 = 0; k2 < K2; k2++) {
            int kc = k2 * 4 + q;
            union { unsigned short s[8]; uint4 qq; } pk;
            #pragma unroll
            for (int j = 0; j < 8; j++)
                pk.s[j] = f2bf(w[(co * CIN + c8 * 8 + j) * K2 + k2]);
            size_t phys = (size_t)(((co >> 4) * 36 + kc)) * 2048 + ks * 1024 + lane16 * 16;
            *(uint4*)((char*)wtb + phys) = pk.qq;
        }
    }
}

// ---------------------------------------------------------------------------
// k_conv: fused-sampling implicit GEMM.
// 512 blocks x 512 thr, 2 blocks/CU (de-phased TLP: the two blocks' barriers
// are unsynchronized, so one block's waves issue while the other stalls).
// Per block: M=256 x N=32 px, K=2304 in 36x64. Wave grid 8m x 1n:
// wave w owns C rows w*32..w*32+31 (2 co-tiles) -> A fragments have ZERO
// n-duplication (per-CU A traffic unchanged vs N=64 x 1 block).
// A: fragment-major wtb straight to regs (4 x 1KB coalesced loads/wave/step),
//    register double-buffered one step ahead.
// B: waves 0-3 gather (2-deep prefetch) + pack (v_pk_fma + cvt_pk_bf16) into
//    double-buffered Bs; waves 4-7 are light (more phase diversity).
// ALL VMEM register-destined -> counted vmcnt; per-step barrier is
// lgkmcnt-only — vmcnt never drained in-loop.
// ---------------------------------------------------------------------------
#define GATHER2(garr, gwarr, kn) do { \
    int k2n_ = (kn) >> 2, qn_ = (kn) & 3; \
    int cb_ = (px0 * K2 + k2n_) * 4; \
    int4   ci_ = *(const int4*)&cidx[cb_]; \
    float4 cw_ = *(const float4*)&cwgt[cb_]; \
    gwarr[0] = cw_.x; gwarr[1] = cw_.y; gwarr[2] = cw_.z; gwarr[3] = cw_.w; \
    const char* xq_ = xb + qn_ * 128; \
    garr[0] = *(const uint4*)(xq_ + ci_.x); \
    garr[1] = *(const uint4*)(xq_ + ci_.y); \
    garr[2] = *(const uint4*)(xq_ + ci_.z); \
    garr[3] = *(const uint4*)(xq_ + ci_.w); \
} while (0)

#define ISSUE_A(Ar) do { \
    Ar[0] = *(const bf16x8*)(ap0);        Ar[1] = *(const bf16x8*)(ap0 + 1024); \
    Ar[2] = *(const bf16x8*)(ap1);        Ar[3] = *(const bf16x8*)(ap1 + 1024); \
    ap0 += 2048; ap1 += 2048; \
} while (0)

#define PACK(garr, gwarr, Bdst) do { \
    f32x2 f0 = {0.f, 0.f}, f1 = {0.f, 0.f}, f2 = {0.f, 0.f}, f3 = {0.f, 0.f}; \
    _Pragma("unroll") \
    for (int c_ = 0; c_ < 4; c_++) { \
        f32x2 wv_ = { gwarr[c_], gwarr[c_] }; \
        f0 = __builtin_elementwise_fma(wv_, up2(garr[c_].x), f0); \
        f1 = __builtin_elementwise_fma(wv_, up2(garr[c_].y), f1); \
        f2 = __builtin_elementwise_fma(wv_, up2(garr[c_].z), f2); \
        f3 = __builtin_elementwise_fma(wv_, up2(garr[c_].w), f3); \
    } \
    uint4 pk_; \
    pk_.x = cvtpk(f0); pk_.y = cvtpk(f1); pk_.z = cvtpk(f2); pk_.w = cvtpk(f3); \
    *(uint4*)&(Bdst)[bofs0] = pk_; \
} while (0)

#define MFMA_STEP(Ar, Bc) do { \
    __builtin_amdgcn_s_setprio(1); \
    _Pragma("unroll") \
    for (int ks_ = 0; ks_ < 2; ks_++) { \
        int up_ = ((ks_ * 4 + hf) ^ skey) * 8; \
        bf16x8 bv_[2]; \
        _Pragma("unroll") \
        for (int ni_ = 0; ni_ < 2; ni_++) \
            bv_[ni_] = *(const bf16x8*)&(Bc)[(ni_ * 16 + r16) * 64 + up_]; \
        _Pragma("unroll") \
        for (int mi_ = 0; mi_ < 2; mi_++) \
            _Pragma("unroll") \
            for (int ni_ = 0; ni_ < 2; ni_++) \
                acc[mi_][ni_] = __builtin_amdgcn_mfma_f32_16x16x32_bf16( \
                    Ar[mi_ * 2 + ks_], bv_[ni_], acc[mi_][ni_], 0, 0, 0); \
    } \
    __builtin_amdgcn_s_setprio(0); \
} while (0)

// lgkm-only barrier: Bs ds_writes drained; in-flight VMEM (A regs, gathers)
// keeps flying across it. sched_barrier pins placement (rule #18).
#define LGKM_BAR() do { \
    asm volatile("s_waitcnt lgkmcnt(0)\n\ts_barrier" ::: "memory"); \
    __builtin_amdgcn_sched_barrier(0); \
} while (0)

#define BODY(kc, Acur, Anxt, Bcur, Bnxt, gU, gwU, gF, gwF) do { \
    ISSUE_A(Anxt); \
    if (heavy) GATHER2(gF, gwF, (kc) + 2); \
    __builtin_amdgcn_sched_barrier(0); \
    MFMA_STEP(Acur, Bcur); \
    __builtin_amdgcn_sched_barrier(0); \
    if (heavy) PACK(gU, gwU, Bnxt); \
    LGKM_BAR(); \
} while (0)

__global__ __launch_bounds__(512, 4)
void k_conv(const unsigned short* __restrict__ wtb, const unsigned short* __restrict__ xh,
            const float* __restrict__ offset, const float* __restrict__ mask,
            const float* __restrict__ bias, float* __restrict__ out,
            float* __restrict__ gstat) {
    __shared__ __align__(16) unsigned short Bs[2][32 * 64];    // 8 KB
    __shared__ __align__(16) int   cidx[32 * K2 * 4];          // 4.5 KB (byte offsets)
    __shared__ __align__(16) float cwgt[32 * K2 * 4];          // 4.5 KB
    __shared__ float gs[32], gss[32];

    // block decode: XCD k = bid&7 owns strips k*64..k*64+63 (contiguous hw)
    int lid = blockIdx.x;
    int strip = (lid & 7) * 64 + (lid >> 3);   // 0..511
    int b = strip >> 7;
    int hwbase = (strip & 127) * 32;

    int t = threadIdx.x, w = t >> 6, l = t & 63;
    int r16 = l & 15, hf = l >> 4;
    int skey = r16 & 7;
    bool heavy = (w < 4);                      // waves 0-3 gather+pack

    if (t < 32) { gs[t] = 0.f; gss[t] = 0.f; }

    // ---- corner prep: 288 (px,k2) pairs (single pass, 512 threads)
    for (int i = t; i < 32 * K2; i += 512) {
        int px = i / K2, k2 = i - px * K2;
        int hw = hwbase + px;
        int ho = hw >> 6, wo = hw & 63;
        int ky = k2 / KKS, kx = k2 - ky * KKS;
        float dy = offset[((b * (2 * K2) + k2 * 2 + 0) * HWSZ) + hw];
        float dx = offset[((b * (2 * K2) + k2 * 2 + 1) * HWSZ) + hw];
        float m  = mask[(b * K2 + k2) * HWSZ + hw];
        float y  = (float)(ky + ho - PADV) + dy;
        float xc = (float)(kx + wo - PADV) + dx;
        float y0f = floorf(y), x0f = floorf(xc);
        float fy = y - y0f, fx = xc - x0f;
        int y0 = (int)y0f, x0 = (int)x0f;
        int   yy[2] = { y0, y0 + 1 };
        int   xx[2] = { x0, x0 + 1 };
        float wy[2] = { 1.f - fy, fy };
        float wx[2] = { 1.f - fx, fx };
        #pragma unroll
        for (int ii = 0; ii < 2; ii++)
            #pragma unroll
            for (int jj = 0; jj < 2; jj++) {
                int yi = yy[ii], xi = xx[jj];
                bool valid = (yi >= 0) && (yi < HH) && (xi >= 0) && (xi < WWID);
                int yc  = min(max(yi, 0), HH - 1);
                int xcc = min(max(xi, 0), WWID - 1);
                cidx[i * 4 + ii * 2 + jj] = (yc * WWID + xcc) << 9;   // byte offset
                cwgt[i * 4 + ii * 2 + jj] = valid ? (wy[ii] * wx[jj] * m) : 0.f;
            }
    }

    // ---- A fragment pointers: wave w owns co-tiles w*2, w*2+1; +2KB per kc
    const char* wb = (const char*)wtb + (size_t)l * 16;
    const char* ap0 = wb + (size_t)((w * 2 + 0) * 36) * 2048;
    const char* ap1 = wb + (size_t)((w * 2 + 1) * 36) * 2048;

    // ---- sampling mapping (heavy waves): px = t>>3 (0..31), sc = t&7
    int sc  = t & 7;
    int px0 = t >> 3;
    const char* xb = (const char*)xh + (size_t)b * HWSZ * CIN * 2 + sc * 16;
    int bofs0 = px0 * 64 + (sc ^ (px0 & 7)) * 8;

    f32x4 acc[2][2];
    #pragma unroll
    for (int mi = 0; mi < 2; mi++)
        #pragma unroll
        for (int ni = 0; ni < 2; ni++) acc[mi][ni] = (f32x4)0.f;

    __syncthreads();   // coef + gs ready

    // ---- prologue
    uint4 gA[4], gB[4]; float gwA[4], gwB[4];
    bf16x8 Aa[4], Ab[4];
    if (heavy) GATHER2(gA, gwA, 0);
    ISSUE_A(Aa);              // A(0)
    if (heavy) {
        GATHER2(gB, gwB, 1);
        PACK(gA, gwA, Bs[0]); // B(0); waits its gathers (counted), A in flight
    }
    LGKM_BAR();

    unsigned short* Bs0 = &Bs[0][0];
    unsigned short* Bs1 = &Bs[1][0];

    // ---- main loop: bodies 0..33 (2-unrolled), then body 34, tail 35
    for (int kc2 = 0; kc2 < 34; kc2 += 2) {
        BODY(kc2,     Aa, Ab, Bs0, Bs1, gB, gwB, gA, gwA);
        BODY(kc2 + 1, Ab, Aa, Bs1, Bs0, gA, gwA, gB, gwB);
    }
    // body 34: issue A(35), MFMA(34), pack B(35) from gB; no gather fill
    ISSUE_A(Ab);
    __builtin_amdgcn_sched_barrier(0);
    MFMA_STEP(Aa, Bs0);
    __builtin_amdgcn_sched_barrier(0);
    if (heavy) PACK(gB, gwB, Bs1);
    LGKM_BAR();
    // tail: kc=35
    MFMA_STEP(Ab, Bs1);

    // ---- epilogue: bias + store + GN partials (C/D: col=lane&15, row=hf*4+r)
    float s4[2] = {0,0}, ss4[2] = {0,0};
    #pragma unroll
    for (int mi = 0; mi < 2; mi++) {
        #pragma unroll
        for (int r = 0; r < 4; r++) {
            int co = w * 32 + mi * 16 + hf * 4 + r;
            float bs = bias[co];
            float* orow = out + ((size_t)(b * COUT + co)) * HWSZ;
            #pragma unroll
            for (int ni = 0; ni < 2; ni++) {
                int n = hwbase + ni * 16 + r16;
                float v = acc[mi][ni][r] + bs;
                orow[n] = v;
                s4[mi] += v; ss4[mi] += v * v;
            }
        }
    }
    int gb = hf >> 1;
    #pragma unroll
    for (int mi = 0; mi < 2; mi++) {
        atomicAdd(&gs [w * 4 + mi * 2 + gb], s4[mi]);
        atomicAdd(&gss[w * 4 + mi * 2 + gb], ss4[mi]);
    }
    __syncthreads();
    if (t < 32) {
        atomicAdd(&gstat[(b * GROUPS + t) * 2 + 0], gs[t]);
        atomicAdd(&gstat[(b * GROUPS + t) * 2 + 1], gss[t]);
    }
}

// ---------------------------------------------------------------------------
// finalize: normalize + affine + ReLU in place (float4)
// ---------------------------------------------------------------------------
__global__ __launch_bounds__(256)
void k_gnfinal(float* __restrict__ out, const float* __restrict__ gstat,
               const float* __restrict__ gamma, const float* __restrict__ beta) {
    int i4 = blockIdx.x * 256 + threadIdx.x;
    int e  = i4 * 4;
    int c  = (e >> 12) & 255;
    int b  = e >> 20;
    int g  = c >> 3;
    float s  = gstat[((b * GROUPS) + g) * 2 + 0];
    float ss = gstat[((b * GROUPS) + g) * 2 + 1];
    const float inv = 1.f / (float)(CPG * HWSZ);
    float mu  = s * inv;
    float var = ss * inv - mu * mu;
    float rstd = rsqrtf(var + EPSV);
    float ga = gamma[c] * rstd;
    float be = beta[c] - mu * ga;
    float4 v = ((float4*)out)[i4];
    v.x = fmaxf(v.x * ga + be, 0.f);
    v.y = fmaxf(v.y * ga + be, 0.f);
    v.z = fmaxf(v.z * ga + be, 0.f);
    v.w = fmaxf(v.w * ga + be, 0.f);
    ((float4*)out)[i4] = v;
}

// ---------------------------------------------------------------------------
extern "C" void kernel_launch(void* const* d_in, const int* in_sizes, int n_in,
                              void* d_out, int out_size, void* d_ws, size_t ws_size,
                              hipStream_t stream) {
    const float* x      = (const float*)d_in[0];
    const float* offset = (const float*)d_in[1];
    const float* mask   = (const float*)d_in[2];
    const float* weight = (const float*)d_in[3];
    const float* bias   = (const float*)d_in[4];
    const float* gamma  = (const float*)d_in[5];
    const float* beta   = (const float*)d_in[6];
    float* out = (float*)d_out;

    // workspace (~10 MB)
    unsigned short* xh    = (unsigned short*)d_ws;              // 4,194,304 us (8.4 MB)
    unsigned short* wtb   = xh + (size_t)4194304;               //   589,824 us (1.2 MB)
    float*          gstat = (float*)(wtb + (size_t)589824);     // 264 f

    k_pre<<<dim3(65, 8, 4), 256, 0, stream>>>(x, xh, weight, wtb, gstat);
    k_conv<<<512, 512, 0, stream>>>(wtb, xh, offset, mask, bias, out, gstat);
    k_gnfinal<<<(size_t)BB * COUT * HWSZ / 1024, 256, 0, stream>>>(out, gstat, gamma, beta);
}

// Round 6
// 135.023 us; speedup vs baseline: 1.1437x; 1.0694x over previous
//
#include <hip/hip_runtime.h>
#include <math.h>

// Problem constants
#define BB    4
#define CIN   256
#define HH    64
#define WWID  64
#define COUT  256
#define KKS   3
#define K2    9
#define PADV  1
#define HWSZ  4096
#define GROUPS 32
#define CPG   8
#define EPSV  1e-5f
#define NKC   36            // K chunks of 64

typedef __attribute__((ext_vector_type(8))) short bf16x8;
typedef __attribute__((ext_vector_type(4))) float f32x4;
typedef __attribute__((ext_vector_type(2))) float f32x2;

__device__ __forceinline__ unsigned short f2bf(float f) {
    unsigned u = __float_as_uint(f);
    u = (u + 0x7fffu + ((u >> 16) & 1u)) >> 16;   // RNE
    return (unsigned short)u;
}
__device__ __forceinline__ f32x2 up2(unsigned q) {
    f32x2 v;
    v.x = __uint_as_float(q << 16);
    v.y = __uint_as_float(q & 0xffff0000u);
    return v;
}
__device__ __forceinline__ unsigned cvtpk(f32x2 f) {
    unsigned r;
    asm("v_cvt_pk_bf16_f32 %0, %1, %2" : "=v"(r) : "v"(f.x), "v"(f.y));
    return r;
}

// ---------------------------------------------------------------------------
// k_pre: grid (65, 8, 4).
//  bx<64 : x NCHW -> NHWC bf16 transpose, 32c x 64hw tiles
//  bx==64: weight [Cout][Cin][K2] -> FRAGMENT-major wtb:
//          byte addr = ((co>>4)*36 + kc)*2048 + ks*1024 + (hf*16 + (co&15))*16
//          so one MFMA A-fragment (lane l reads bytes l*16..l*16+15) is a
//          single 1KB contiguous, fully-coalesced global_load_dwordx4.
//          block (64,0,0) zeroes gstat.
// ---------------------------------------------------------------------------
__global__ __launch_bounds__(256)
void k_pre(const float* __restrict__ x, unsigned short* __restrict__ xh,
           const float* __restrict__ w, unsigned short* __restrict__ wtb,
           float* __restrict__ gstat) {
    int t = threadIdx.x;
    if (blockIdx.x < 64) {
        __shared__ float tile[32][65];
        int hw0 = blockIdx.x * 64;
        int c0  = blockIdx.y * 32;
        int b   = blockIdx.z;
        const float* xp = x + (size_t)b * CIN * HWSZ;
        int col = t & 63, r0 = t >> 6;
        #pragma unroll
        for (int i = 0; i < 8; i++)
            tile[i * 4 + r0][col] = xp[(c0 + i * 4 + r0) * HWSZ + hw0 + col];
        __syncthreads();
        int hw = t >> 2, cq = t & 3;
        union { unsigned short s[8]; uint4 qq; } pk;
        #pragma unroll
        for (int k = 0; k < 8; k++) pk.s[k] = f2bf(tile[cq * 8 + k][hw]);
        *(uint4*)((char*)xh + (((size_t)b * HWSZ + hw0 + hw) * CIN + c0 + cq * 8) * 2) = pk.qq;
    } else {
        if (blockIdx.y == 0 && blockIdx.z == 0)
            for (int i = t; i < BB * GROUPS * 2 + 8; i += 256) gstat[i] = 0.f;
        int idx = (blockIdx.y * 4 + blockIdx.z) * 256 + t;   // [0,8192)
        int co = idx >> 5, c8 = idx & 31;
        int q  = c8 >> 3;                // 64-ch chunk within 256
        int ks = (c8 & 7) >> 2;          // K-half within 64-chunk
        int hf = c8 & 3;                 // 8-ch slice within 32
        int lane16 = hf * 16 + (co & 15);
        for (int k2 = 0; k2 < K2; k2++) {
            int kc = k2 * 4 + q;
            union { unsigned short s[8]; uint4 qq; } pk;
            #pragma unroll
            for (int j = 0; j < 8; j++)
                pk.s[j] = f2bf(w[(co * CIN + c8 * 8 + j) * K2 + k2]);
            size_t phys = (size_t)(((co >> 4) * 36 + kc)) * 2048 + ks * 1024 + lane16 * 16;
            *(uint4*)((char*)wtb + phys) = pk.qq;
        }
    }
}

// ---------------------------------------------------------------------------
// k_conv: fused-sampling implicit GEMM — VMEM-traffic-minimal tiling.
// 256 blocks x 512 thr (1 block/CU). M=256 x N=64, K=2304 in 36x64.
// Wave grid 8m x 1n: wave w owns C rows w*32..w*32+31, ALL 64 px ->
// every A fragment read ONCE per CU per step: A = 32 KB/CU/step (was 64),
// gathers 32 KB -> total 64 KB/CU/step vs 96 in r4/r5 (both 57.4 µs,
// proving VMEM-throughput-bound; latency/TLP ruled out by r5).
// A: fragment-major wtb straight to regs (4 x 1KB coalesced loads/wave/step),
//    register double-buffered one step ahead.
// B: every thread gathers+packs 1 item (64 px x 8 sc), 2-deep prefetch,
//    v_pk_fma + cvt_pk_bf16, Bs LDS double-buffered.
// ALL VMEM register-destined -> counted vmcnt; per-step barrier is
// lgkmcnt-only — vmcnt never drained in-loop.
// ---------------------------------------------------------------------------
#define GATHER2(garr, gwarr, kn) do { \
    int k2n_ = (kn) >> 2, qn_ = (kn) & 3; \
    int cb_ = (px0 * K2 + k2n_) * 4; \
    int4   ci_ = *(const int4*)&cidx[cb_]; \
    float4 cw_ = *(const float4*)&cwgt[cb_]; \
    gwarr[0] = cw_.x; gwarr[1] = cw_.y; gwarr[2] = cw_.z; gwarr[3] = cw_.w; \
    const char* xq_ = xb + qn_ * 128; \
    garr[0] = *(const uint4*)(xq_ + ci_.x); \
    garr[1] = *(const uint4*)(xq_ + ci_.y); \
    garr[2] = *(const uint4*)(xq_ + ci_.z); \
    garr[3] = *(const uint4*)(xq_ + ci_.w); \
} while (0)

#define ISSUE_A(Ar) do { \
    Ar[0] = *(const bf16x8*)(ap0);        Ar[1] = *(const bf16x8*)(ap0 + 1024); \
    Ar[2] = *(const bf16x8*)(ap1);        Ar[3] = *(const bf16x8*)(ap1 + 1024); \
    ap0 += 2048; ap1 += 2048; \
} while (0)

#define PACK(garr, gwarr, Bdst) do { \
    f32x2 f0 = {0.f, 0.f}, f1 = {0.f, 0.f}, f2 = {0.f, 0.f}, f3 = {0.f, 0.f}; \
    _Pragma("unroll") \
    for (int c_ = 0; c_ < 4; c_++) { \
        f32x2 wv_ = { gwarr[c_], gwarr[c_] }; \
        f0 = __builtin_elementwise_fma(wv_, up2(garr[c_].x), f0); \
        f1 = __builtin_elementwise_fma(wv_, up2(garr[c_].y), f1); \
        f2 = __builtin_elementwise_fma(wv_, up2(garr[c_].z), f2); \
        f3 = __builtin_elementwise_fma(wv_, up2(garr[c_].w), f3); \
    } \
    uint4 pk_; \
    pk_.x = cvtpk(f0); pk_.y = cvtpk(f1); pk_.z = cvtpk(f2); pk_.w = cvtpk(f3); \
    *(uint4*)&(Bdst)[bofs0] = pk_; \
} while (0)

#define MFMA_STEP(Ar, Bc) do { \
    __builtin_amdgcn_s_setprio(1); \
    _Pragma("unroll") \
    for (int ks_ = 0; ks_ < 2; ks_++) { \
        int up_ = ((ks_ * 4 + hf) ^ skey) * 8; \
        bf16x8 bv_[4]; \
        _Pragma("unroll") \
        for (int ni_ = 0; ni_ < 4; ni_++) \
            bv_[ni_] = *(const bf16x8*)&(Bc)[(ni_ * 16 + r16) * 64 + up_]; \
        _Pragma("unroll") \
        for (int mi_ = 0; mi_ < 2; mi_++) \
            _Pragma("unroll") \
            for (int ni_ = 0; ni_ < 4; ni_++) \
                acc[mi_][ni_] = __builtin_amdgcn_mfma_f32_16x16x32_bf16( \
                    Ar[mi_ * 2 + ks_], bv_[ni_], acc[mi_][ni_], 0, 0, 0); \
    } \
    __builtin_amdgcn_s_setprio(0); \
} while (0)

// lgkm-only barrier: Bs ds_writes drained; in-flight VMEM (A regs, gathers)
// keeps flying across it. sched_barrier pins placement (rule #18).
#define LGKM_BAR() do { \
    asm volatile("s_waitcnt lgkmcnt(0)\n\ts_barrier" ::: "memory"); \
    __builtin_amdgcn_sched_barrier(0); \
} while (0)

#define BODY(kc, Acur, Anxt, Bcur, Bnxt, gU, gwU, gF, gwF) do { \
    ISSUE_A(Anxt); \
    GATHER2(gF, gwF, (kc) + 2); \
    __builtin_amdgcn_sched_barrier(0); \
    MFMA_STEP(Acur, Bcur); \
    __builtin_amdgcn_sched_barrier(0); \
    PACK(gU, gwU, Bnxt); \
    LGKM_BAR(); \
} while (0)

__global__ __launch_bounds__(512, 2)
void k_conv(const unsigned short* __restrict__ wtb, const unsigned short* __restrict__ xh,
            const float* __restrict__ offset, const float* __restrict__ mask,
            const float* __restrict__ bias, float* __restrict__ out,
            float* __restrict__ gstat) {
    __shared__ __align__(16) unsigned short Bs[2][64 * 64];    // 16 KB
    __shared__ __align__(16) int   cidx[64 * K2 * 4];          // 9 KB (byte offsets)
    __shared__ __align__(16) float cwgt[64 * K2 * 4];          // 9 KB
    __shared__ float gs[32], gss[32];

    // block decode: XCD k = bid&7 owns strips k*32..k*32+31 (contiguous hw)
    int lid = blockIdx.x;
    int strip = (lid & 7) * 32 + (lid >> 3);   // 0..255
    int b = strip >> 6;
    int hwbase = (strip & 63) * 64;

    int t = threadIdx.x, w = t >> 6, l = t & 63;
    int r16 = l & 15, hf = l >> 4;
    int skey = r16 & 7;

    if (t < 32) { gs[t] = 0.f; gss[t] = 0.f; }

    // ---- corner prep: 576 (px,k2) pairs
    for (int i = t; i < 64 * K2; i += 512) {
        int px = i / K2, k2 = i - px * K2;
        int hw = hwbase + px;
        int ho = hw >> 6, wo = hw & 63;
        int ky = k2 / KKS, kx = k2 - ky * KKS;
        float dy = offset[((b * (2 * K2) + k2 * 2 + 0) * HWSZ) + hw];
        float dx = offset[((b * (2 * K2) + k2 * 2 + 1) * HWSZ) + hw];
        float m  = mask[(b * K2 + k2) * HWSZ + hw];
        float y  = (float)(ky + ho - PADV) + dy;
        float xc = (float)(kx + wo - PADV) + dx;
        float y0f = floorf(y), x0f = floorf(xc);
        float fy = y - y0f, fx = xc - x0f;
        int y0 = (int)y0f, x0 = (int)x0f;
        int   yy[2] = { y0, y0 + 1 };
        int   xx[2] = { x0, x0 + 1 };
        float wy[2] = { 1.f - fy, fy };
        float wx[2] = { 1.f - fx, fx };
        #pragma unroll
        for (int ii = 0; ii < 2; ii++)
            #pragma unroll
            for (int jj = 0; jj < 2; jj++) {
                int yi = yy[ii], xi = xx[jj];
                bool valid = (yi >= 0) && (yi < HH) && (xi >= 0) && (xi < WWID);
                int yc  = min(max(yi, 0), HH - 1);
                int xcc = min(max(xi, 0), WWID - 1);
                cidx[i * 4 + ii * 2 + jj] = (yc * WWID + xcc) << 9;   // byte offset
                cwgt[i * 4 + ii * 2 + jj] = valid ? (wy[ii] * wx[jj] * m) : 0.f;
            }
    }

    // ---- A fragment pointers: wave w owns co-tiles w*2, w*2+1; +2KB per kc
    const char* wb = (const char*)wtb + (size_t)l * 16;
    const char* ap0 = wb + (size_t)((w * 2 + 0) * 36) * 2048;
    const char* ap1 = wb + (size_t)((w * 2 + 1) * 36) * 2048;

    // ---- sampling mapping: 1 item/thread: px = t>>3 (0..63), sc = t&7
    int sc  = t & 7;
    int px0 = t >> 3;
    const char* xb = (const char*)xh + (size_t)b * HWSZ * CIN * 2 + sc * 16;
    int bofs0 = px0 * 64 + (sc ^ (px0 & 7)) * 8;

    f32x4 acc[2][4];
    #pragma unroll
    for (int mi = 0; mi < 2; mi++)
        #pragma unroll
        for (int ni = 0; ni < 4; ni++) acc[mi][ni] = (f32x4)0.f;

    __syncthreads();   // coef + gs ready

    // ---- prologue
    uint4 gA[4], gB[4]; float gwA[4], gwB[4];
    bf16x8 Aa[4], Ab[4];
    GATHER2(gA, gwA, 0);
    ISSUE_A(Aa);              // A(0)
    GATHER2(gB, gwB, 1);
    PACK(gA, gwA, Bs[0]);     // B(0); waits its gathers (counted), A in flight
    LGKM_BAR();

    unsigned short* Bs0 = &Bs[0][0];
    unsigned short* Bs1 = &Bs[1][0];

    // ---- main loop: bodies 0..33 (2-unrolled), then body 34, tail 35
    for (int kc2 = 0; kc2 < 34; kc2 += 2) {
        BODY(kc2,     Aa, Ab, Bs0, Bs1, gB, gwB, gA, gwA);
        BODY(kc2 + 1, Ab, Aa, Bs1, Bs0, gA, gwA, gB, gwB);
    }
    // body 34: issue A(35), MFMA(34), pack B(35) from gB; no gather fill
    ISSUE_A(Ab);
    __builtin_amdgcn_sched_barrier(0);
    MFMA_STEP(Aa, Bs0);
    __builtin_amdgcn_sched_barrier(0);
    PACK(gB, gwB, Bs1);
    LGKM_BAR();
    // tail: kc=35
    MFMA_STEP(Ab, Bs1);

    // ---- epilogue: bias + store + GN partials (C/D: col=lane&15, row=hf*4+r)
    float s4[2] = {0,0}, ss4[2] = {0,0};
    #pragma unroll
    for (int mi = 0; mi < 2; mi++) {
        #pragma unroll
        for (int r = 0; r < 4; r++) {
            int co = w * 32 + mi * 16 + hf * 4 + r;
            float bs = bias[co];
            float* orow = out + ((size_t)(b * COUT + co)) * HWSZ;
            #pragma unroll
            for (int ni = 0; ni < 4; ni++) {
                int n = hwbase + ni * 16 + r16;
                float v = acc[mi][ni][r] + bs;
                orow[n] = v;
                s4[mi] += v; ss4[mi] += v * v;
            }
        }
    }
    int gb = hf >> 1;
    #pragma unroll
    for (int mi = 0; mi < 2; mi++) {
        atomicAdd(&gs [w * 4 + mi * 2 + gb], s4[mi]);
        atomicAdd(&gss[w * 4 + mi * 2 + gb], ss4[mi]);
    }
    __syncthreads();
    if (t < 32) {
        atomicAdd(&gstat[(b * GROUPS + t) * 2 + 0], gs[t]);
        atomicAdd(&gstat[(b * GROUPS + t) * 2 + 1], gss[t]);
    }
}

// ---------------------------------------------------------------------------
// finalize: normalize + affine + ReLU in place (float4)
// ---------------------------------------------------------------------------
__global__ __launch_bounds__(256)
void k_gnfinal(float* __restrict__ out, const float* __restrict__ gstat,
               const float* __restrict__ gamma, const float* __restrict__ beta) {
    int i4 = blockIdx.x * 256 + threadIdx.x;
    int e  = i4 * 4;
    int c  = (e >> 12) & 255;
    int b  = e >> 20;
    int g  = c >> 3;
    float s  = gstat[((b * GROUPS) + g) * 2 + 0];
    float ss = gstat[((b * GROUPS) + g) * 2 + 1];
    const float inv = 1.f / (float)(CPG * HWSZ);
    float mu  = s * inv;
    float var = ss * inv - mu * mu;
    float rstd = rsqrtf(var + EPSV);
    float ga = gamma[c] * rstd;
    float be = beta[c] - mu * ga;
    float4 v = ((float4*)out)[i4];
    v.x = fmaxf(v.x * ga + be, 0.f);
    v.y = fmaxf(v.y * ga + be, 0.f);
    v.z = fmaxf(v.z * ga + be, 0.f);
    v.w = fmaxf(v.w * ga + be, 0.f);
    ((float4*)out)[i4] = v;
}

// ---------------------------------------------------------------------------
extern "C" void kernel_launch(void* const* d_in, const int* in_sizes, int n_in,
                              void* d_out, int out_size, void* d_ws, size_t ws_size,
                              hipStream_t stream) {
    const float* x      = (const float*)d_in[0];
    const float* offset = (const float*)d_in[1];
    const float* mask   = (const float*)d_in[2];
    const float* weight = (const float*)d_in[3];
    const float* bias   = (const float*)d_in[4];
    const float* gamma  = (const float*)d_in[5];
    const float* beta   = (const float*)d_in[6];
    float* out = (float*)d_out;

    // workspace (~10 MB)
    unsigned short* xh    = (unsigned short*)d_ws;              // 4,194,304 us (8.4 MB)
    unsigned short* wtb   = xh + (size_t)4194304;               //   589,824 us (1.2 MB)
    float*          gstat = (float*)(wtb + (size_t)589824);     // 264 f

    k_pre<<<dim3(65, 8, 4), 256, 0, stream>>>(x, xh, weight, wtb, gstat);
    k_conv<<<256, 512, 0, stream>>>(wtb, xh, offset, mask, bias, out, gstat);
    k_gnfinal<<<(size_t)BB * COUT * HWSZ / 1024, 256, 0, stream>>>(out, gstat, gamma, beta);
}